// Round 15
// baseline (820.776 us; speedup 1.0000x reference)
//
#include <hip/hip_runtime.h>
#include <stdint.h>

#define NBATCH 16384
#define TT     20
#define CC     256
#define LDB    264   // bf16 feat/sT row stride (u16): 528B -> 2-way bank alias (free)
#define TP     32    // sVT inner stride (u16): 64B rows
#define NT     256   // 4 waves
#define BPB    32    // batches per block; grid = 512 = 2 blocks/CU

typedef __bf16 bf16x8 __attribute__((ext_vector_type(8)));
typedef float  f32x4  __attribute__((ext_vector_type(4)));

// lgkm-only barrier: LDS writes visible, global loads stay in flight
#define BAR_LGKM() do { asm volatile("s_waitcnt lgkmcnt(0)" ::: "memory"); \
                        __builtin_amdgcn_s_barrier(); } while (0)

// tb_mask tables: t=0,1:{0,1,2} t=2:{0,1,2,3} t=3..15:{t,t+1} t=16:uniform t=17..19:{17,18,19}
__constant__ int8_t c_CNT[TT] = {3,3,4,2,2,2,2,2,2,2,2,2,2,2,2,2,0,3,3,3};
__constant__ int8_t c_OFF[TT] = {0,3,6,10,12,14,16,18,20,22,24,26,28,30,32,34,0,36,39,42};
__constant__ int8_t c_PT[45]  = {0,0,0,1,1,1,2,2,2,2,3,3,4,4,5,5,6,6,7,7,8,8,9,9,
                                 10,10,11,11,12,12,13,13,14,14,15,15,17,17,17,18,18,18,19,19,19};
__constant__ int8_t c_PS[45]  = {0,1,2,0,1,2,0,1,2,3,3,4,4,5,5,6,6,7,7,8,8,9,9,10,
                                 10,11,11,12,12,13,13,14,14,15,15,16,17,18,19,17,18,19,17,18,19};

__device__ __forceinline__ uint16_t f2bf(float f) {
    __bf16 b = (__bf16)f;
    return __builtin_bit_cast(uint16_t, b);
}
__device__ __forceinline__ uint32_t pk2(float a, float b) {
    return (uint32_t)f2bf(a) | ((uint32_t)f2bf(b) << 16);
}
__device__ __forceinline__ float bflo(uint32_t u) { return __builtin_bit_cast(float, u << 16); }
__device__ __forceinline__ float bfhi(uint32_t u) { return __builtin_bit_cast(float, u & 0xffff0000u); }

// prep1: mqkT[n][k] = sum_h Wk[h,n]*Wq[h,k] / 16 ;  wvb[n][k] = bf16(Wv[n][k])
__global__ void prep1_kernel(const float* __restrict__ Wq, const float* __restrict__ Wk,
                             const float* __restrict__ Wv, uint16_t* __restrict__ mqkT,
                             uint16_t* __restrict__ wvb) {
    const int n = blockIdx.x;
    const int k = threadIdx.x;
    float acc = 0.f;
    for (int h = 0; h < CC; ++h)
        acc = fmaf(Wk[h * CC + n], Wq[h * CC + k], acc);
    mqkT[n * CC + k] = f2bf(acc * 0.0625f);
    wvb[n * CC + k]  = f2bf(Wv[n * CC + k]);
}

// prep2: swizzle tables into per-wave MFMA fragment order (one coalesced 1KB load per frag)
__global__ void prep2_kernel(const uint16_t* __restrict__ mqkT, const uint16_t* __restrict__ wvb,
                             uint16_t* __restrict__ BqS, uint16_t* __restrict__ BvS) {
    const int bid = blockIdx.x;          // 0..63 : m*32 + w*8 + kk
    const int m  = bid >> 5;
    const int w  = (bid >> 3) & 3;
    const int kk = bid & 7;
    const int ct   = threadIdx.x >> 6;
    const int lane = threadIdx.x & 63;
    const uint16_t* src = m ? wvb : mqkT;
    uint16_t*       dst = m ? BvS : BqS;
    const int n   = w * 64 + ct * 16 + (lane & 15);
    const int col = kk * 32 + ((lane >> 4) << 3);
    uint4 v = *(const uint4*)(src + n * CC + col);
    *(uint4*)(dst + ((size_t)((w * 32 + kk * 4 + ct) * 64 + lane) << 3)) = v;
}

// bf16 fragment: single b128 from row r, 8-elem unit u
__device__ __forceinline__ bf16x8 ldb(const uint16_t* __restrict__ s, int r, int u) {
    return __builtin_bit_cast(bf16x8, *(const uint4*)(s + r * LDB + (u << 3)));
}

__global__ __launch_bounds__(NT, 2)
void attn_main(const float* __restrict__ f1g, const float* __restrict__ f2g,
               const uint16_t* __restrict__ BqS, const uint16_t* __restrict__ BvS,
               float* __restrict__ outg) {
    // 60096 B -> 2 blocks/CU. Layout (u16 offsets):
    //   buf0: f1 @0,    f2 @5280   | buf1: f1 @10560, f2 @15840
    //   sVT @21120 ([256][TP] = 8192), attnL @29312 (640), s_simE @29952 (45 f32 = 90 u16)
    __shared__ uint16_t smem[30048];
    uint16_t* sVT    = smem + 21120;
    uint16_t* attnL  = smem + 29312;
    float*    s_simE = (float*)(smem + 29952);

    const int tid  = threadIdx.x;
    const int lane = tid & 63;
    const int w    = tid >> 6;             // wave owns 64 hid cols
    const int l15  = lane & 15;
    const int q    = lane >> 4;
    const size_t bbase = (size_t)blockIdx.x * BPB * TT * CC;

    const uint16_t* bq = BqS + ((size_t)w << 14);
    const uint16_t* bv = BvS + ((size_t)w << 14);
    const int rB0 = l15;
    const int rB1 = (16 + l15 < TT) ? 16 + l15 : TT - 1;

    // ---- prologue: stage batch 0 -> buf 0; prefill attnL (persists across iters) ----
    {
        const float* f1 = f1g + bbase;
        const float* f2 = f2g + bbase;
        float4 va[5], vb[5];
#pragma unroll
        for (int j = 0; j < 5; ++j) {
            int s = tid + (j << 8);
            va[j] = *(const float4*)(f1 + (s << 2));
            vb[j] = *(const float4*)(f2 + (s << 2));
        }
        {   // attnL: zeros; row16 cols0..19 = 1.0 (uniform-row trick). Written once.
            uint32_t* aL = (uint32_t*)attnL;
#pragma unroll
            for (int rep = 0; rep < 2; ++rep) {
                int s = tid + (rep << 8);
                if (s < 320)
                    aL[s] = ((s >> 4) == 16 && (s & 15) < 10) ? 0x3F803F80u : 0u;
            }
        }
#pragma unroll
        for (int j = 0; j < 5; ++j) {
            int s  = tid + (j << 8);
            int r  = s >> 6;
            int c4 = (s & 63) << 2;
            uint2 u1; u1.x = pk2(va[j].x, va[j].y); u1.y = pk2(va[j].z, va[j].w);
            uint2 u2; u2.x = pk2(vb[j].x, vb[j].y); u2.y = pk2(vb[j].z, vb[j].w);
            *(uint2*)&smem[r * LDB + c4] = u1;          // buf0 f1
            *(uint2*)&smem[5280 + r * LDB + c4] = u2;   // buf0 f2
        }
    }
    BAR_LGKM();

    for (int i = 0; i < BPB; ++i) {
        const int curOf = (i & 1) ? 10560 : 0;
        const int nxtOf = (i & 1) ? 0 : 10560;
        const bool hasNext = (i + 1 < BPB);
        const uint16_t* f1b = smem + curOf;
        const uint16_t* f2b = smem + curOf + 5280;
        uint16_t* sT = smem + nxtOf;           // t1 scratch = next f1 buffer (freed by phase C)
        uint16_t* w2 = smem + nxtOf + 5280;

        // ---- top: issue next batch's loads (in flight across the whole iteration) ----
        float4 pa[5], pb[5];
        if (hasNext) {
            const float* f1n = f1g + bbase + (size_t)(i + 1) * TT * CC;
            const float* f2n = f2g + bbase + (size_t)(i + 1) * TT * CC;
#pragma unroll
            for (int j = 0; j < 5; ++j) {
                int s = tid + (j << 8);
                pa[j] = *(const float4*)(f1n + (s << 2));
                pb[j] = *(const float4*)(f2n + (s << 2));
            }
            __builtin_amdgcn_sched_barrier(0);   // pin load issue before compute
        }

        // ---- phase A: GEMM1 swapped (A=Mqk frags, B=feat1^T) -> t1^T -> sT ----
        {
            f32x4 acc[4][2];
#pragma unroll
            for (int mt = 0; mt < 4; ++mt)
#pragma unroll
                for (int ct = 0; ct < 2; ++ct)
                    acc[mt][ct] = f32x4{0.f, 0.f, 0.f, 0.f};
#pragma unroll
            for (int kk = 0; kk < 8; ++kk) {
                const int u = (kk << 2) + q;
                bf16x8 b0 = ldb(f1b, rB0, u);
                bf16x8 b1 = ldb(f1b, rB1, u);
#pragma unroll
                for (int mt = 0; mt < 4; ++mt) {
                    bf16x8 am = __builtin_bit_cast(bf16x8,
                        *(const uint4*)(bq + (((kk << 2) + mt) * 64 + lane) * 8));
                    acc[mt][0] = __builtin_amdgcn_mfma_f32_16x16x32_bf16(am, b0, acc[mt][0], 0, 0, 0);
                    acc[mt][1] = __builtin_amdgcn_mfma_f32_16x16x32_bf16(am, b1, acc[mt][1], 0, 0, 0);
                }
            }
            // D: t1^T[h = w*64+mt*16+4q+j][t = ct*16+l15] -> sT[t][h]
#pragma unroll
            for (int mt = 0; mt < 4; ++mt)
#pragma unroll
                for (int ct = 0; ct < 2; ++ct) {
                    int t = ct * 16 + l15;
                    if (t < TT) {
                        int h0 = (w << 6) + mt * 16 + (q << 2);
                        uint2 u2;
                        u2.x = pk2(acc[mt][ct][0], acc[mt][ct][1]);
                        u2.y = pk2(acc[mt][ct][2], acc[mt][ct][3]);
                        *(uint2*)&sT[t * LDB + h0] = u2;
                    }
                }
        }
        BAR_LGKM();   // A: sT visible

        // ---- phase B: sim+exp (180 thr) and GEMM2 -> sVT ----
        if (tid < 180) {
            int d = tid >> 2;
            int p = tid & 3;
            int t = c_PT[d], s = c_PS[d];
            const uint16_t* ap = sT  + t * LDB + (p << 3);
            const uint16_t* bp = f2b + s * LDB + (p << 3);
            float da = 0.f;
#pragma unroll
            for (int c = 0; c < 256; c += 32) {
                uint4 ua = *(const uint4*)(ap + c);
                uint4 ub = *(const uint4*)(bp + c);
                da = fmaf(bflo(ua.x), bflo(ub.x), da);
                da = fmaf(bfhi(ua.x), bfhi(ub.x), da);
                da = fmaf(bflo(ua.y), bflo(ub.y), da);
                da = fmaf(bfhi(ua.y), bfhi(ub.y), da);
                da = fmaf(bflo(ua.z), bflo(ub.z), da);
                da = fmaf(bfhi(ua.z), bfhi(ub.z), da);
                da = fmaf(bflo(ua.w), bflo(ub.w), da);
                da = fmaf(bfhi(ua.w), bfhi(ub.w), da);
            }
            da += __shfl_xor(da, 1);
            da += __shfl_xor(da, 2);
            if (p == 0) {
                float e = __expf(da);
                attnL[t * 32 + s] = f2bf(e);
                s_simE[d] = e;
            }
        }
        {
            f32x4 av[2][4];
#pragma unroll
            for (int rt = 0; rt < 2; ++rt)
#pragma unroll
                for (int ct = 0; ct < 4; ++ct)
                    av[rt][ct] = f32x4{0.f, 0.f, 0.f, 0.f};
#pragma unroll
            for (int kk = 0; kk < 8; ++kk) {
                const int u = (kk << 2) + q;
                bf16x8 a0 = ldb(f2b, rB0, u);
                bf16x8 a1 = ldb(f2b, rB1, u);
#pragma unroll
                for (int ct = 0; ct < 4; ++ct) {
                    bf16x8 bm = __builtin_bit_cast(bf16x8,
                        *(const uint4*)(bv + (((kk << 2) + ct) * 64 + lane) * 8));
                    av[0][ct] = __builtin_amdgcn_mfma_f32_16x16x32_bf16(a0, bm, av[0][ct], 0, 0, 0);
                    av[1][ct] = __builtin_amdgcn_mfma_f32_16x16x32_bf16(a1, bm, av[1][ct], 0, 0, 0);
                }
            }
            // D: v[t = rt*16+4q+j][h = w*64+ct*16+l15] -> sVT[h][t]; zeros for t=20..31
#pragma unroll
            for (int ct = 0; ct < 4; ++ct) {
                int h = (w << 6) + ct * 16 + l15;
                {
                    uint2 u2;
                    u2.x = pk2(av[0][ct][0], av[0][ct][1]);
                    u2.y = pk2(av[0][ct][2], av[0][ct][3]);
                    *(uint2*)&sVT[h * TP + (q << 2)] = u2;
                }
                {
                    uint2 u2;
                    if (q == 0) {
                        u2.x = pk2(av[1][ct][0], av[1][ct][1]);
                        u2.y = pk2(av[1][ct][2], av[1][ct][3]);
                    } else { u2.x = 0u; u2.y = 0u; }
                    *(uint2*)&sVT[h * TP + 16 + (q << 2)] = u2;
                }
            }
        }
        BAR_LGKM();   // B: sVT + attnL + simE visible; sT readers done

        // ---- phase C: PV via MFMA + normalize-at-store; then write next stage ----
        {
            bf16x8 pa0 = __builtin_bit_cast(bf16x8, *(const uint4*)&attnL[l15 * 32 + (q << 3)]);
            bf16x8 pa1 = __builtin_bit_cast(bf16x8, *(const uint4*)&attnL[(16 + l15) * 32 + (q << 3)]);
            const f32x4 z = f32x4{0.f, 0.f, 0.f, 0.f};
            f32x4 o[2][4];
#pragma unroll
            for (int ct = 0; ct < 4; ++ct) {
                bf16x8 pbv = __builtin_bit_cast(bf16x8,
                    *(const uint4*)&sVT[((w << 6) + ct * 16 + l15) * TP + (q << 3)]);
                o[0][ct] = __builtin_amdgcn_mfma_f32_16x16x32_bf16(pa0, pbv, z, 0, 0, 0);
                o[1][ct] = __builtin_amdgcn_mfma_f32_16x16x32_bf16(pa1, pbv, z, 0, 0, 0);
            }
            const size_t ob = bbase + (size_t)i * TT * CC;
#pragma unroll
            for (int rt = 0; rt < 2; ++rt)
#pragma unroll
                for (int j = 0; j < 4; ++j) {
                    int t = rt * 16 + (q << 2) + j;
                    if (t < TT) {
                        int cnt = c_CNT[t], off = c_OFF[t];
                        float rs = (cnt == 0) ? 20.0f : s_simE[off];
#pragma unroll
                        for (int jj = 1; jj < 4; ++jj)
                            if (jj < cnt) rs += s_simE[off + jj];
                        float iv = __builtin_amdgcn_rcpf(rs);
                        float* op = outg + ob + (size_t)t * CC + (w << 6) + l15;
#pragma unroll
                        for (int ct = 0; ct < 4; ++ct)
                            op[ct * 16] = o[rt][ct][j] * iv;
                    }
                }
        }
        if (hasNext) {   // consume prefetch: cvt + ds_write into buf[nxt] (over sT / f2)
#pragma unroll
            for (int j = 0; j < 5; ++j) {
                int s  = tid + (j << 8);
                int r  = s >> 6;
                int c4 = (s & 63) << 2;
                uint2 u1; u1.x = pk2(pa[j].x, pa[j].y); u1.y = pk2(pa[j].z, pa[j].w);
                uint2 u2; u2.x = pk2(pb[j].x, pb[j].y); u2.y = pk2(pb[j].z, pb[j].w);
                *(uint2*)&sT[r * LDB + c4] = u1;   // sT region == buf[nxt] f1
                *(uint2*)&w2[r * LDB + c4] = u2;
            }
        }
        BAR_LGKM();   // C: next buffers staged; sVT/attnL free
    }
}

extern "C" void kernel_launch(void* const* d_in, const int* in_sizes, int n_in,
                              void* d_out, int out_size, void* d_ws, size_t ws_size,
                              hipStream_t stream) {
    const float* feat1 = (const float*)d_in[0];
    const float* feat2 = (const float*)d_in[1];
    const float* Wq    = (const float*)d_in[2];
    const float* Wk    = (const float*)d_in[3];
    const float* Wv    = (const float*)d_in[4];
    uint16_t* mqkT = (uint16_t*)d_ws;          // 128 KB
    uint16_t* wvb  = mqkT + CC * CC;           // 128 KB
    uint16_t* BqS  = wvb  + CC * CC;           // 128 KB (fragment-ordered)
    uint16_t* BvS  = BqS  + CC * CC;           // 128 KB (fragment-ordered)

    prep1_kernel<<<CC, CC, 0, stream>>>(Wq, Wk, Wv, mqkT, wvb);
    prep2_kernel<<<64, NT, 0, stream>>>(mqkT, wvb, BqS, BvS);
    attn_main<<<NBATCH / BPB, NT, 0, stream>>>(feat1, feat2, BqS, BvS, (float*)d_out);
}